// Round 7
// baseline (640.596 us; speedup 1.0000x reference)
//
#include <hip/hip_runtime.h>
#include <math.h>

#define N_NODES 100000
#define N_EDGES 3200000
#define NH 16               // channels per stack
#define SST (N_NODES * NH)  // per-stack element stride in t/h buffers
#define BN_EPS 1e-5f
#define NBUCK 196        // ceil(100000/512) buckets of 512 nodes
#define BSHIFT 9
#define BMASK 511
#define EPB 16384        // edges per block in bucket scatter
#define NBLK1 196        // ceil(N_EDGES/EPB)
#define CAP 18432        // fixed bucket capacity: mean 16327 + 16 sigma
#define FIX 16777216.0f  // 2^24 fixed point for degree sums
#define NBLKS 6250       // blocks per stack in conv1_prop (16 nodes/block)

typedef unsigned long long u64;
typedef unsigned int u32;
typedef unsigned short u16;

__device__ __forceinline__ u16 f2bf(float f) {
  u32 b = __float_as_uint(f);
  b += 0x7FFFu + ((b >> 16) & 1u);   // RNE
  return (u16)(b >> 16);
}
__device__ __forceinline__ float bf2f(u32 s) {
  return __uint_as_float(s << 16);
}

// ---------------- K1: scatter edges into FIXED-CAPACITY buckets -------------
__global__ __launch_bounds__(1024) void bucket_scatter_kernel(
    const int* __restrict__ row, const int* __restrict__ col,
    const float* __restrict__ ea, u32* __restrict__ gcur,
    int2* __restrict__ bucketed) {
  __shared__ u32 bins[NBUCK];
  __shared__ u32 base[NBUCK];
  __shared__ u16 rnk[EPB];
  for (int t = threadIdx.x; t < NBUCK; t += 1024) bins[t] = 0;
  __syncthreads();
  int eb = blockIdx.x * EPB;
  for (int it = 0; it < EPB / 1024; ++it) {
    int i = it * 1024 + threadIdx.x;
    int e = eb + i;
    if (e < N_EDGES) rnk[i] = (u16)atomicAdd(&bins[col[e] >> BSHIFT], 1u);
  }
  __syncthreads();
  for (int t = threadIdx.x; t < NBUCK; t += 1024) {
    u32 c = bins[t];
    if (c) base[t] = (u32)t * CAP + atomicAdd(&gcur[t * 8], c);
  }
  __syncthreads();
  for (int it = 0; it < EPB / 1024; ++it) {
    int i = it * 1024 + threadIdx.x;
    int e = eb + i;
    if (e < N_EDGES) {
      int c = col[e];
      int bkt = c >> BSHIFT, cl = c & BMASK;
      u32 pos = base[bkt] + (u32)rnk[i];
      bucketed[pos] = make_int2((cl << 17) | row[e], __float_as_int(ea[e]));
    }
  }
}

// ---------------- P2: FUSED per-bucket offs/dinv/zx + csr fill --------------
__global__ __launch_bounds__(1024) void node_offs_csr_kernel(
    const int2* __restrict__ bucketed, const u32* __restrict__ gcur,
    const float* __restrict__ x,
    int* __restrict__ offs, float* __restrict__ dinv, u16* __restrict__ zx,
    u32* __restrict__ csr) {
  __shared__ u32 cnt[512];
  __shared__ u32 degf[512];
  __shared__ u32 cur[512];
  __shared__ u32 red[256];
  __shared__ u32 shmeta[2];   // [0]=bstart, [1]=fill
  int t = threadIdx.x;
  int b = blockIdx.x;
  if (t < 512) { cnt[t] = 0; degf[t] = 0; }
  if (t < 256) red[t] = (t < b) ? gcur[t * 8] : 0;   // NBUCK<256
  __syncthreads();
  for (int d = 128; d; d >>= 1) {
    if (t < d) red[t] += red[t + d];
    __syncthreads();
  }
  if (t == 0) { shmeta[0] = red[0]; shmeta[1] = gcur[b * 8]; }
  __syncthreads();
  u32 bst = shmeta[0], fill = shmeta[1];
  u32 s_pad = (u32)b * CAP;
  for (u32 i = t; i < fill; i += 1024) {
    int2 v = bucketed[s_pad + i];
    int cl = (v.x >> 17) & BMASK;
    atomicAdd(&cnt[cl], 1u);
    atomicAdd(&degf[cl], (u32)(__int_as_float(v.y) * FIX));
  }
  __syncthreads();
  u32 v0 = (t < 512) ? cnt[t] : 0;
  for (int d = 1; d < 512; d <<= 1) {
    u32 u = (t < 512 && t >= d) ? cnt[t - d] : 0;
    __syncthreads();
    if (t < 512) cnt[t] += u;
    __syncthreads();
  }
  int n = b * 512 + t;
  if (t < 512) {
    if (n < N_NODES) {
      u32 off0 = bst + cnt[t] - v0;   // exclusive, compact
      offs[n] = (int)off0;
      cur[t] = off0;
      float dg = (float)degf[t] * (1.0f / FIX);
      float dv = dg > 0.f ? rsqrtf(fmaxf(dg, 1e-12f)) : 0.f;
      dinv[n] = dv;
      zx[n] = f2bf(x[n] * dv);
    } else {
      cur[t] = 0;
    }
  }
  if (b == 0 && t == 0) offs[N_NODES] = N_EDGES;
  __syncthreads();
  for (u32 i = t; i < fill; i += 1024) {
    int2 v = bucketed[s_pad + i];
    int cl = (v.x >> 17) & BMASK;
    u32 r = (u32)(v.x & 0x1FFFF);
    u16 w = f2bf(__int_as_float(v.y));   // ea >= 0 -> sign bit 0, w < 0x8000
    u32 pos = atomicAdd(&cur[cl], 1u);
    csr[pos] = (r << 15) | (u32)w;
  }
}

// ---------------- layer-1: scalar prop + epilogue + transform (merged) ------
// Writes tout in per-stack layout: [K][N][16]
__global__ __launch_bounds__(256) void sprop_mid_kernel(
    const u32* __restrict__ csr, const int* __restrict__ offs,
    const u16* __restrict__ zx, const float* __restrict__ dinv,
    const float* __restrict__ x,
    const float* __restrict__ w1i, const float* __restrict__ w1r,
    const float* __restrict__ b1, const float* __restrict__ w1,
    u16* __restrict__ tout) {
  int t = blockIdx.x * 256 + threadIdx.x;
  int n = t >> 4, c = t & 15;
  float a = 0.f;
  int s = offs[n], e = offs[n + 1];
  for (int i = s + c; i < e; i += 16) {
    u32 ee = __builtin_nontemporal_load(csr + i);
    a += bf2f(ee & 0x7FFFu) * bf2f((u32)zx[ee >> 15]);
  }
#pragma unroll
  for (int o = 8; o; o >>= 1) a += __shfl_xor(a, o, 64);
  float dn = dinv[n];
  float sn = a * dn;
  float xn = x[n];
  int base = (threadIdx.x & 63) & 48;
#pragma unroll
  for (int k = 0; k < 3; ++k) {
    float u = fmaxf(sn * w1i[k * 16 + c] + xn * w1r[k * 16 + c] + b1[k * 16 + c], 0.f);
    float tf = 0.f;
#pragma unroll
    for (int f = 0; f < 16; ++f) tf += __shfl(u, base + f, 64) * w1[k * 256 + f * 16 + c];
    tout[(size_t)k * SST + (size_t)n * NH + c] = f2bf(tf * dn);
  }
}

// ---------------- conv1 propagate: PER-STACK, k-partitioned grid ------------
// wave = 4 groups x 16 channel-lanes; group = one node of stack k.
// Per-stack table = 3.2 MB < 4 MB L2 -> gathers are L2 hits after warmup.
// csr loads are per-edge INDEPENDENT dwords (group-uniform addr, broadcast);
// 8-edge unroll -> 16 VMEM in flight, dependency chains of depth 2.
__global__ __launch_bounds__(256) void conv1_prop_kernel(
    const u16* __restrict__ tin, u16* __restrict__ tout, float* __restrict__ hbuf3,
    const u32* __restrict__ csr, const int* __restrict__ offs,
    const float* __restrict__ dinv, const float* __restrict__ x,
    const float* __restrict__ w1r, const float* __restrict__ b1,
    const float* __restrict__ w1, int do_t) {
  int k = blockIdx.x / NBLKS;
  int bid = blockIdx.x - k * NBLKS;
  int lane = threadIdx.x & 63;
  int g = lane >> 4;          // group 0..3
  int c = lane & 15;          // channel 0..15
  int wix = ((bid << 8) + (int)threadIdx.x) >> 6;   // wave idx within stack
  int n = wix * 4 + g;        // 25000 waves * 4 groups = 100000 nodes exactly
  const u16* __restrict__ tk = tin + (size_t)k * SST;
  float rb = w1r[k * NH + c];
  float bb = b1[k * NH + c];
  float wreg[16];
  if (do_t) {
#pragma unroll
    for (int f = 0; f < 16; ++f) wreg[f] = w1[k * 256 + f * NH + c];
  }
  int s = offs[n], e = offs[n + 1];
  float dn = dinv[n];
  float xn = x[n];
  float acc = 0.f;
  int i = s;
  for (; i + 8 <= e; i += 8) {
    u32 a0 = __builtin_nontemporal_load(csr + i);
    u32 a1 = __builtin_nontemporal_load(csr + i + 1);
    u32 a2 = __builtin_nontemporal_load(csr + i + 2);
    u32 a3 = __builtin_nontemporal_load(csr + i + 3);
    u32 a4 = __builtin_nontemporal_load(csr + i + 4);
    u32 a5 = __builtin_nontemporal_load(csr + i + 5);
    u32 a6 = __builtin_nontemporal_load(csr + i + 6);
    u32 a7 = __builtin_nontemporal_load(csr + i + 7);
    float v0 = bf2f((u32)tk[(a0 >> 15) * NH + c]);
    float v1 = bf2f((u32)tk[(a1 >> 15) * NH + c]);
    float v2 = bf2f((u32)tk[(a2 >> 15) * NH + c]);
    float v3 = bf2f((u32)tk[(a3 >> 15) * NH + c]);
    float v4 = bf2f((u32)tk[(a4 >> 15) * NH + c]);
    float v5 = bf2f((u32)tk[(a5 >> 15) * NH + c]);
    float v6 = bf2f((u32)tk[(a6 >> 15) * NH + c]);
    float v7 = bf2f((u32)tk[(a7 >> 15) * NH + c]);
    acc += bf2f(a0 & 0x7FFFu) * v0 + bf2f(a1 & 0x7FFFu) * v1 +
           bf2f(a2 & 0x7FFFu) * v2 + bf2f(a3 & 0x7FFFu) * v3 +
           bf2f(a4 & 0x7FFFu) * v4 + bf2f(a5 & 0x7FFFu) * v5 +
           bf2f(a6 & 0x7FFFu) * v6 + bf2f(a7 & 0x7FFFu) * v7;
  }
  for (; i + 4 <= e; i += 4) {
    u32 a0 = __builtin_nontemporal_load(csr + i);
    u32 a1 = __builtin_nontemporal_load(csr + i + 1);
    u32 a2 = __builtin_nontemporal_load(csr + i + 2);
    u32 a3 = __builtin_nontemporal_load(csr + i + 3);
    float v0 = bf2f((u32)tk[(a0 >> 15) * NH + c]);
    float v1 = bf2f((u32)tk[(a1 >> 15) * NH + c]);
    float v2 = bf2f((u32)tk[(a2 >> 15) * NH + c]);
    float v3 = bf2f((u32)tk[(a3 >> 15) * NH + c]);
    acc += bf2f(a0 & 0x7FFFu) * v0 + bf2f(a1 & 0x7FFFu) * v1 +
           bf2f(a2 & 0x7FFFu) * v2 + bf2f(a3 & 0x7FFFu) * v3;
  }
  for (; i < e; ++i) {
    u32 a0 = __builtin_nontemporal_load(csr + i);
    acc += bf2f(a0 & 0x7FFFu) * bf2f((u32)tk[(a0 >> 15) * NH + c]);
  }
  float u = fmaxf(acc * dn + xn * rb + bb, 0.f);
  if (do_t) {
    float tf = 0.f;
    int base = g * 16;
#pragma unroll
    for (int f = 0; f < 16; ++f) tf += __shfl(u, base + f, 64) * wreg[f];
    tout[(size_t)k * SST + (size_t)n * NH + c] = f2bf(tf * dn);
  } else {
    hbuf3[(size_t)k * SST + (size_t)n * NH + c] = u;
  }
}

// ---------------- BN stats over hbuf3 [3][N,16]: stats of per-node mean -----
__global__ __launch_bounds__(256) void bn_stats_kernel(
    const float* __restrict__ h, double* __restrict__ stats) {
  __shared__ float ssum[NH], ssq[NH];
  int tid = threadIdx.x;
  if (tid < NH) { ssum[tid] = 0.f; ssq[tid] = 0.f; }
  __syncthreads();
  int n = blockIdx.x * blockDim.x + tid;
  bool valid = n < N_NODES;
  size_t base = (size_t)(valid ? n : 0) * NH;
  const float4* p0 = (const float4*)(h + base);
  const float4* p1 = (const float4*)(h + (size_t)SST + base);
  const float4* p2 = (const float4*)(h + 2 * (size_t)SST + base);
  float hv[NH];
#pragma unroll
  for (int q = 0; q < 4; ++q) {
    float4 a = valid ? p0[q] : make_float4(0.f, 0.f, 0.f, 0.f);
    float4 b = valid ? p1[q] : make_float4(0.f, 0.f, 0.f, 0.f);
    float4 d = valid ? p2[q] : make_float4(0.f, 0.f, 0.f, 0.f);
    hv[q * 4 + 0] = (a.x + b.x + d.x) * (1.f / 3.f);
    hv[q * 4 + 1] = (a.y + b.y + d.y) * (1.f / 3.f);
    hv[q * 4 + 2] = (a.z + b.z + d.z) * (1.f / 3.f);
    hv[q * 4 + 3] = (a.w + b.w + d.w) * (1.f / 3.f);
  }
#pragma unroll
  for (int f = 0; f < NH; ++f) {
    float s = hv[f], q = hv[f] * hv[f];
    for (int o = 32; o; o >>= 1) { s += __shfl_xor(s, o, 64); q += __shfl_xor(q, o, 64); }
    if ((tid & 63) == 0) { atomicAdd(&ssum[f], s); atomicAdd(&ssq[f], q); }
  }
  __syncthreads();
  if (tid < NH) {
    atomicAdd(&stats[tid], (double)ssum[tid]);
    atomicAdd(&stats[NH + tid], (double)ssq[tid]);
  }
}

__global__ __launch_bounds__(64) void bn_final_kernel(
    const double* __restrict__ stats, const float* __restrict__ g,
    const float* __restrict__ b, float* __restrict__ sc, float* __restrict__ sh) {
  int f = threadIdx.x;
  if (f < NH) {
    double mu = stats[f] / (double)N_NODES;
    double var = stats[NH + f] / (double)N_NODES - mu * mu;
    float scale = g[f] * (float)(1.0 / sqrt(var + (double)BN_EPS));
    sc[f] = scale;
    sh[f] = b[f] - (float)mu * scale;
  }
}

// ---------------- conv2 init: mean over k + BN-apply + relu + init/root -----
__global__ __launch_bounds__(256) void conv2_init_kernel(
    const float* __restrict__ h, const float* __restrict__ sc, const float* __restrict__ sh,
    const float* __restrict__ dinv,
    const float* __restrict__ w2i, const float* __restrict__ w2r, const float* __restrict__ b2,
    float* __restrict__ P, float* __restrict__ R) {
  int n = blockIdx.x * blockDim.x + threadIdx.x;
  if (n >= N_NODES) return;
  size_t base = (size_t)n * NH;
  float u[NH];
#pragma unroll
  for (int f = 0; f < NH; ++f) {
    float m = (h[base + f] + h[(size_t)SST + base + f] + h[2 * (size_t)SST + base + f]) * (1.f / 3.f);
    u[f] = fmaxf(m * sc[f] + sh[f], 0.f);
  }
  float dn = dinv[n];
#pragma unroll
  for (int k = 0; k < 3; ++k) {
    float r = b2[k], o = 0.f;
#pragma unroll
    for (int f = 0; f < NH; ++f) {
      r += u[f] * w2r[k * NH + f];
      o += u[f] * w2i[k * NH + f];
    }
    R[n * 4 + k] = r;
    P[n * 4 + k] = o * dn;
  }
  R[n * 4 + 3] = 0.f;
  P[n * 4 + 3] = 0.f;
}

// ---------------- conv2 propagate: 16-lane groups, packed CSR ---------------
__global__ __launch_bounds__(256) void conv2_prop_kernel(
    const float* __restrict__ in4, float* __restrict__ out4, float* __restrict__ y,
    const u32* __restrict__ csr, const int* __restrict__ offs,
    const float* __restrict__ dinv,
    const float* __restrict__ R, const float* __restrict__ w2,
    int scale_w2, int final_out) {
  int t = blockIdx.x * 256 + threadIdx.x;
  int n = t >> 4, sub = t & 15;
  float m0 = 1.f, m1 = 1.f, m2 = 1.f;
  if (scale_w2) { m0 = w2[0]; m1 = w2[1]; m2 = w2[2]; }
  int s = offs[n], e = offs[n + 1];
  float a0 = 0.f, a1 = 0.f, a2 = 0.f;
  for (int i = s + sub; i < e; i += 16) {
    u32 ee = __builtin_nontemporal_load(csr + i);
    float w = bf2f(ee & 0x7FFFu);
    const float4 v = *(const float4*)(in4 + (size_t)(ee >> 15) * 4);
    a0 += w * v.x;
    a1 += w * v.y;
    a2 += w * v.z;
  }
#pragma unroll
  for (int o = 8; o; o >>= 1) {
    a0 += __shfl_xor(a0, o, 64);
    a1 += __shfl_xor(a1, o, 64);
    a2 += __shfl_xor(a2, o, 64);
  }
  if (sub == 0) {
    float dn = dinv[n];
    a0 = a0 * dn * m0 + R[n * 4 + 0];
    a1 = a1 * dn * m1 + R[n * 4 + 1];
    a2 = a2 * dn * m2 + R[n * 4 + 2];
    if (final_out) {
      float sm = (a0 + a1 + a2) * (1.f / 3.f);
      y[n] = 1.f / (1.f + expf(-sm));
    } else {
      out4[n * 4 + 0] = a0 * dn;
      out4[n * 4 + 1] = a1 * dn;
      out4[n * 4 + 2] = a2 * dn;
      out4[n * 4 + 3] = 0.f;
    }
  }
}

extern "C" void kernel_launch(void* const* d_in, const int* in_sizes, int n_in,
                              void* d_out, int out_size, void* d_ws, size_t ws_size,
                              hipStream_t stream) {
  const float* x   = (const float*)d_in[0];
  const int*   ei  = (const int*)d_in[1];
  const float* ea  = (const float*)d_in[2];
  // d_in[3] = batch (unused)
  const float* w1i = (const float*)d_in[4];
  const float* w1  = (const float*)d_in[5];
  const float* w1r = (const float*)d_in[6];
  const float* b1  = (const float*)d_in[7];
  const float* bng = (const float*)d_in[8];
  const float* bnb = (const float*)d_in[9];
  const float* w2i = (const float*)d_in[10];
  const float* w2  = (const float*)d_in[11];
  const float* w2r = (const float*)d_in[12];
  const float* b2  = (const float*)d_in[13];
  float* y = (float*)d_out;

  const int* row = ei;
  const int* col = ei + N_EDGES;

  char* ws = (char*)d_ws;
  size_t off = 0;
  auto alloc = [&](size_t bytes) -> char* {
    char* p = ws + off;
    off += (bytes + 255) & ~(size_t)255;
    return p;
  };
  u32*    gcur   = (u32*)alloc((size_t)NBUCK * 8 * 4);
  int*    offs   = (int*)alloc((size_t)(N_NODES + 1) * 4);
  float*  dinv   = (float*)alloc((size_t)N_NODES * 4);
  u16*    zx     = (u16*)alloc((size_t)N_NODES * 2);
  double* stats  = (double*)alloc(32 * 8);
  float*  bnsc   = (float*)alloc(16 * 4);
  float*  bnsh   = (float*)alloc(16 * 4);
  int2*   bucketed = (int2*)alloc((size_t)NBUCK * CAP * 8);
  u32*    csr    = (u32*)alloc((size_t)N_EDGES * 4);
  u16*    tA     = (u16*)alloc((size_t)3 * SST * 2);
  u16*    tB     = (u16*)alloc((size_t)3 * SST * 2);
  float*  hbuf   = (float*)alloc((size_t)3 * SST * 4);
  float*  P2     = (float*)alloc((size_t)N_NODES * 4 * 4);
  float*  Q2     = (float*)alloc((size_t)N_NODES * 4 * 4);
  float*  R2     = (float*)alloc((size_t)N_NODES * 4 * 4);
  (void)ws_size; (void)in_sizes; (void)n_in; (void)out_size;

  hipMemsetAsync(gcur, 0, (size_t)NBUCK * 8 * 4, stream);
  hipMemsetAsync(stats, 0, 32 * 8, stream);

  bucket_scatter_kernel<<<NBLK1, 1024, 0, stream>>>(row, col, ea, gcur, bucketed);
  node_offs_csr_kernel<<<NBUCK, 1024, 0, stream>>>(bucketed, gcur, x, offs, dinv, zx, csr);

  const int NPB = 6250;  // N_NODES*16/256 exactly
  // conv1 layer 1 (rank-1 collapse): merged scalar prop + dense epilogue -> tA
  sprop_mid_kernel<<<NPB, 256, 0, stream>>>(csr, offs, zx, dinv, x, w1i, w1r, b1, w1, tA);
  // conv1 layers 2-4: per-stack propagation, k-partitioned grid (3 x 6250)
  conv1_prop_kernel<<<3 * NBLKS, 256, 0, stream>>>(tA, tB, nullptr, csr, offs, dinv, x, w1r, b1, w1, 1);
  conv1_prop_kernel<<<3 * NBLKS, 256, 0, stream>>>(tB, tA, nullptr, csr, offs, dinv, x, w1r, b1, w1, 1);
  conv1_prop_kernel<<<3 * NBLKS, 256, 0, stream>>>(tA, nullptr, hbuf, csr, offs, dinv, x, w1r, b1, w1, 0);

  bn_stats_kernel<<<(N_NODES + 255) / 256, 256, 0, stream>>>(hbuf, stats);
  bn_final_kernel<<<1, 64, 0, stream>>>(stats, bng, bnb, bnsc, bnsh);
  conv2_init_kernel<<<(N_NODES + 255) / 256, 256, 0, stream>>>(
      hbuf, bnsc, bnsh, dinv, w2i, w2r, b2, P2, R2);

  conv2_prop_kernel<<<NPB, 256, 0, stream>>>(P2, Q2, nullptr, csr, offs, dinv, R2, w2, 0, 0);
  conv2_prop_kernel<<<NPB, 256, 0, stream>>>(Q2, P2, nullptr, csr, offs, dinv, R2, w2, 1, 0);
  conv2_prop_kernel<<<NPB, 256, 0, stream>>>(P2, Q2, nullptr, csr, offs, dinv, R2, w2, 1, 0);
  conv2_prop_kernel<<<NPB, 256, 0, stream>>>(Q2, P2, y, csr, offs, dinv, R2, w2, 1, 1);
}

// Round 8
// 490.135 us; speedup vs baseline: 1.3070x; 1.3070x over previous
//
#include <hip/hip_runtime.h>
#include <math.h>

#define N_NODES 100000
#define N_EDGES 3200000
#define KH 48            // K*H active channels
#define FDIM 64          // padded feature row stride (128 B, line-aligned)
#define NH 16            // H
#define BN_EPS 1e-5f
#define NBUCK 196        // ceil(100000/512) buckets of 512 nodes
#define BSHIFT 9
#define BMASK 511
#define EPB 16384        // edges per block in bucket scatter
#define NBLK1 196        // ceil(N_EDGES/EPB)
#define CAP 18432        // fixed bucket capacity: mean 16327 + 16 sigma
#define FIX 16777216.0f  // 2^24 fixed point for degree sums

typedef unsigned long long u64;
typedef unsigned int u32;
typedef unsigned short u16;

__device__ __forceinline__ u16 f2bf(float f) {
  u32 b = __float_as_uint(f);
  b += 0x7FFFu + ((b >> 16) & 1u);   // RNE
  return (u16)(b >> 16);
}
__device__ __forceinline__ float bf2f(u32 s) {
  return __uint_as_float(s << 16);
}
__device__ __forceinline__ u32 rfl(u32 v) {
  return (u32)__builtin_amdgcn_readfirstlane((int)v);
}

// ---------------- K1: scatter edges into FIXED-CAPACITY buckets -------------
__global__ __launch_bounds__(1024) void bucket_scatter_kernel(
    const int* __restrict__ row, const int* __restrict__ col,
    const float* __restrict__ ea, u32* __restrict__ gcur,
    int2* __restrict__ bucketed) {
  __shared__ u32 bins[NBUCK];
  __shared__ u32 base[NBUCK];
  __shared__ u16 rnk[EPB];
  for (int t = threadIdx.x; t < NBUCK; t += 1024) bins[t] = 0;
  __syncthreads();
  int eb = blockIdx.x * EPB;
  for (int it = 0; it < EPB / 1024; ++it) {
    int i = it * 1024 + threadIdx.x;
    int e = eb + i;
    if (e < N_EDGES) rnk[i] = (u16)atomicAdd(&bins[col[e] >> BSHIFT], 1u);
  }
  __syncthreads();
  for (int t = threadIdx.x; t < NBUCK; t += 1024) {
    u32 c = bins[t];
    if (c) base[t] = (u32)t * CAP + atomicAdd(&gcur[t * 8], c);
  }
  __syncthreads();
  for (int it = 0; it < EPB / 1024; ++it) {
    int i = it * 1024 + threadIdx.x;
    int e = eb + i;
    if (e < N_EDGES) {
      int c = col[e];
      int bkt = c >> BSHIFT, cl = c & BMASK;
      u32 pos = base[bkt] + (u32)rnk[i];
      bucketed[pos] = make_int2((cl << 17) | row[e], __float_as_int(ea[e]));
    }
  }
}

// ---------------- P2: FUSED per-bucket offs/dinv/zx + csr fill --------------
__global__ __launch_bounds__(1024) void node_offs_csr_kernel(
    const int2* __restrict__ bucketed, const u32* __restrict__ gcur,
    const float* __restrict__ x,
    int* __restrict__ offs, float* __restrict__ dinv, u16* __restrict__ zx,
    u32* __restrict__ csr) {
  __shared__ u32 cnt[512];
  __shared__ u32 degf[512];
  __shared__ u32 cur[512];
  __shared__ u32 red[256];
  __shared__ u32 shmeta[2];   // [0]=bstart, [1]=fill
  int t = threadIdx.x;
  int b = blockIdx.x;
  if (t < 512) { cnt[t] = 0; degf[t] = 0; }
  if (t < 256) red[t] = (t < b) ? gcur[t * 8] : 0;   // NBUCK<256
  __syncthreads();
  for (int d = 128; d; d >>= 1) {
    if (t < d) red[t] += red[t + d];
    __syncthreads();
  }
  if (t == 0) { shmeta[0] = red[0]; shmeta[1] = gcur[b * 8]; }
  __syncthreads();
  u32 bst = shmeta[0], fill = shmeta[1];
  u32 s_pad = (u32)b * CAP;
  for (u32 i = t; i < fill; i += 1024) {
    int2 v = bucketed[s_pad + i];
    int cl = (v.x >> 17) & BMASK;
    atomicAdd(&cnt[cl], 1u);
    atomicAdd(&degf[cl], (u32)(__int_as_float(v.y) * FIX));
  }
  __syncthreads();
  u32 v0 = (t < 512) ? cnt[t] : 0;
  for (int d = 1; d < 512; d <<= 1) {
    u32 u = (t < 512 && t >= d) ? cnt[t - d] : 0;
    __syncthreads();
    if (t < 512) cnt[t] += u;
    __syncthreads();
  }
  int n = b * 512 + t;
  if (t < 512) {
    if (n < N_NODES) {
      u32 off0 = bst + cnt[t] - v0;   // exclusive, compact
      offs[n] = (int)off0;
      cur[t] = off0;
      float dg = (float)degf[t] * (1.0f / FIX);
      float dv = dg > 0.f ? rsqrtf(fmaxf(dg, 1e-12f)) : 0.f;
      dinv[n] = dv;
      zx[n] = f2bf(x[n] * dv);
    } else {
      cur[t] = 0;
    }
  }
  if (b == 0 && t == 0) offs[N_NODES] = N_EDGES;
  __syncthreads();
  for (u32 i = t; i < fill; i += 1024) {
    int2 v = bucketed[s_pad + i];
    int cl = (v.x >> 17) & BMASK;
    u32 r = (u32)(v.x & 0x1FFFF);
    u16 w = f2bf(__int_as_float(v.y));   // ea >= 0 -> sign bit 0, w < 0x8000
    u32 pos = atomicAdd(&cur[cl], 1u);
    csr[pos] = (r << 15) | (u32)w;
  }
}

// ---------------- layer-1: scalar prop + epilogue + transform (merged) ------
__global__ __launch_bounds__(256) void sprop_mid_kernel(
    const u32* __restrict__ csr, const int* __restrict__ offs,
    const u16* __restrict__ zx, const float* __restrict__ dinv,
    const float* __restrict__ x,
    const float* __restrict__ w1i, const float* __restrict__ w1r,
    const float* __restrict__ b1, const float* __restrict__ w1,
    u16* __restrict__ tout) {
  int t = blockIdx.x * 256 + threadIdx.x;
  int n = t >> 4, c = t & 15;
  float a = 0.f;
  int s = offs[n], e = offs[n + 1];
  for (int i = s + c; i < e; i += 16) {
    u32 ee = csr[i];
    a += bf2f(ee & 0x7FFFu) * bf2f((u32)zx[ee >> 15]);
  }
#pragma unroll
  for (int o = 8; o; o >>= 1) a += __shfl_xor(a, o, 64);
  float dn = dinv[n];
  float sn = a * dn;
  float xn = x[n];
  int base = (threadIdx.x & 63) & 48;
#pragma unroll
  for (int k = 0; k < 3; ++k) {
    float u = fmaxf(sn * w1i[k * 16 + c] + xn * w1r[k * 16 + c] + b1[k * 16 + c], 0.f);
    float tf = 0.f;
#pragma unroll
    for (int f = 0; f < 16; ++f) tf += __shfl(u, base + f, 64) * w1[k * 256 + f * 16 + c];
    tout[(size_t)n * FDIM + k * 16 + c] = f2bf(tf * dn);
  }
}

// ---------------- conv1 propagate, all 3 stacks combined --------------------
// wave per node, lane = channel, 48 active; rows 128 B line-aligned.
// Scalar-path csr (readfirstlane -> SGPR) + GATHER PING-PONG: two 16-gather
// blocks outstanding (32 VMEM in flight per wave) before the first is
// consumed -> doubles in-flight bytes to attack LLC latency exposure.
#define DECL16(p) u32 p##0, p##1, p##2, p##3, p##4, p##5, p##6, p##7, \
                      p##8, p##9, p##10, p##11, p##12, p##13, p##14, p##15
#define LOAD16(p, base) \
  p##0 = rfl(csr[(base)]);      p##1 = rfl(csr[(base) + 1]);  \
  p##2 = rfl(csr[(base) + 2]);  p##3 = rfl(csr[(base) + 3]);  \
  p##4 = rfl(csr[(base) + 4]);  p##5 = rfl(csr[(base) + 5]);  \
  p##6 = rfl(csr[(base) + 6]);  p##7 = rfl(csr[(base) + 7]);  \
  p##8 = rfl(csr[(base) + 8]);  p##9 = rfl(csr[(base) + 9]);  \
  p##10 = rfl(csr[(base) + 10]); p##11 = rfl(csr[(base) + 11]); \
  p##12 = rfl(csr[(base) + 12]); p##13 = rfl(csr[(base) + 13]); \
  p##14 = rfl(csr[(base) + 14]); p##15 = rfl(csr[(base) + 15])
#define GATH16(g, p) \
  g##0 = (u32)tin[(p##0 >> 15) * FDIM + c];  \
  g##1 = (u32)tin[(p##1 >> 15) * FDIM + c];  \
  g##2 = (u32)tin[(p##2 >> 15) * FDIM + c];  \
  g##3 = (u32)tin[(p##3 >> 15) * FDIM + c];  \
  g##4 = (u32)tin[(p##4 >> 15) * FDIM + c];  \
  g##5 = (u32)tin[(p##5 >> 15) * FDIM + c];  \
  g##6 = (u32)tin[(p##6 >> 15) * FDIM + c];  \
  g##7 = (u32)tin[(p##7 >> 15) * FDIM + c];  \
  g##8 = (u32)tin[(p##8 >> 15) * FDIM + c];  \
  g##9 = (u32)tin[(p##9 >> 15) * FDIM + c];  \
  g##10 = (u32)tin[(p##10 >> 15) * FDIM + c]; \
  g##11 = (u32)tin[(p##11 >> 15) * FDIM + c]; \
  g##12 = (u32)tin[(p##12 >> 15) * FDIM + c]; \
  g##13 = (u32)tin[(p##13 >> 15) * FDIM + c]; \
  g##14 = (u32)tin[(p##14 >> 15) * FDIM + c]; \
  g##15 = (u32)tin[(p##15 >> 15) * FDIM + c]
#define FMA16(p, g) \
  acc += bf2f(p##0 & 0x7FFFu) * bf2f(g##0) + bf2f(p##1 & 0x7FFFu) * bf2f(g##1) + \
         bf2f(p##2 & 0x7FFFu) * bf2f(g##2) + bf2f(p##3 & 0x7FFFu) * bf2f(g##3) + \
         bf2f(p##4 & 0x7FFFu) * bf2f(g##4) + bf2f(p##5 & 0x7FFFu) * bf2f(g##5) + \
         bf2f(p##6 & 0x7FFFu) * bf2f(g##6) + bf2f(p##7 & 0x7FFFu) * bf2f(g##7) + \
         bf2f(p##8 & 0x7FFFu) * bf2f(g##8) + bf2f(p##9 & 0x7FFFu) * bf2f(g##9) + \
         bf2f(p##10 & 0x7FFFu) * bf2f(g##10) + bf2f(p##11 & 0x7FFFu) * bf2f(g##11) + \
         bf2f(p##12 & 0x7FFFu) * bf2f(g##12) + bf2f(p##13 & 0x7FFFu) * bf2f(g##13) + \
         bf2f(p##14 & 0x7FFFu) * bf2f(g##14) + bf2f(p##15 & 0x7FFFu) * bf2f(g##15)

__global__ __launch_bounds__(256) void conv1_prop_kernel(
    const u16* __restrict__ tin, u16* __restrict__ tout, float* __restrict__ hbuf,
    const u32* __restrict__ csr, const int* __restrict__ offs,
    const float* __restrict__ dinv, const float* __restrict__ x,
    const float* __restrict__ w1r, const float* __restrict__ b1,
    const float* __restrict__ w1, int do_t) {
  int lane = threadIdx.x & 63;
  int wid = (blockIdx.x * blockDim.x + threadIdx.x) >> 6;
  int nw = (gridDim.x * blockDim.x) >> 6;
  int c = lane;
  bool act = c < KH;
  float rb = act ? w1r[c] : 0.f;
  float bb = act ? b1[c] : 0.f;
  float wreg[16];
  if (do_t) {
    int k = c >> 4, o = c & 15;
    if (act) {
#pragma unroll
      for (int f = 0; f < 16; ++f) wreg[f] = w1[k * 256 + f * 16 + o];
    } else {
#pragma unroll
      for (int f = 0; f < 16; ++f) wreg[f] = 0.f;
    }
  }
  for (int n = wid; n < N_NODES; n += nw) {
    int nu = __builtin_amdgcn_readfirstlane(n);
    int s = __builtin_amdgcn_readfirstlane(offs[nu]);
    int e = __builtin_amdgcn_readfirstlane(offs[nu + 1]);
    float acc = 0.f;
    int i = s;
    int nblk = (e - s) >> 4;
    if (nblk >= 2) {
      DECL16(a);
      DECL16(b);
      DECL16(ga);
      DECL16(gb);
      LOAD16(a, i);
      GATH16(ga, a);           // 16 gathers in flight
      LOAD16(b, i + 16);
      GATH16(gb, b);           // 32 gathers in flight
      int blk = 2;
      for (; blk + 2 <= nblk; blk += 2) {
        FMA16(a, ga);          // waits only on ga; gb still in flight
        LOAD16(a, i + 32);
        GATH16(ga, a);         // refill -> back to 32 in flight
        FMA16(b, gb);
        LOAD16(b, i + 48);
        GATH16(gb, b);
        i += 32;
      }
      FMA16(a, ga);
      FMA16(b, gb);
      i += 32;
      if (blk < nblk) {        // one leftover 16-block
        LOAD16(a, i);
        GATH16(ga, a);
        FMA16(a, ga);
        i += 16;
      }
    } else if (nblk == 1) {
      DECL16(a);
      DECL16(ga);
      LOAD16(a, i);
      GATH16(ga, a);
      FMA16(a, ga);
      i += 16;
    }
    for (; i + 4 <= e; i += 4) {
      u32 e0 = rfl(csr[i]);
      u32 e1 = rfl(csr[i + 1]);
      u32 e2 = rfl(csr[i + 2]);
      u32 e3 = rfl(csr[i + 3]);
      float v0 = bf2f((u32)tin[(e0 >> 15) * FDIM + c]);
      float v1 = bf2f((u32)tin[(e1 >> 15) * FDIM + c]);
      float v2 = bf2f((u32)tin[(e2 >> 15) * FDIM + c]);
      float v3 = bf2f((u32)tin[(e3 >> 15) * FDIM + c]);
      acc += bf2f(e0 & 0x7FFFu) * v0 + bf2f(e1 & 0x7FFFu) * v1 +
             bf2f(e2 & 0x7FFFu) * v2 + bf2f(e3 & 0x7FFFu) * v3;
    }
    for (; i < e; ++i) {
      u32 ee = rfl(csr[i]);
      acc += bf2f(ee & 0x7FFFu) * bf2f((u32)tin[(ee >> 15) * FDIM + c]);
    }
    float dn = dinv[nu];
    float u = fmaxf(acc * dn + x[nu] * rb + bb, 0.f);
    if (do_t) {
      float tf = 0.f;
      int base = c & 48;
#pragma unroll
      for (int f = 0; f < 16; ++f) tf += __shfl(u, base + f, 64) * wreg[f];
      if (act) tout[(size_t)nu * FDIM + c] = f2bf(tf * dn);
    } else {
      float m1v = __shfl(u, lane + 16, 64);
      float m2v = __shfl(u, lane + 32, 64);
      if (lane < NH) hbuf[(size_t)nu * NH + lane] = (u + m1v + m2v) * (1.f / 3.f);
    }
  }
}

// ---------------- BN stats over hbuf [N,16] ---------------------------------
__global__ __launch_bounds__(256) void bn_stats_kernel(
    const float* __restrict__ h, double* __restrict__ stats) {
  __shared__ float ssum[NH], ssq[NH];
  int tid = threadIdx.x;
  if (tid < NH) { ssum[tid] = 0.f; ssq[tid] = 0.f; }
  __syncthreads();
  int n = blockIdx.x * blockDim.x + tid;
  bool valid = n < N_NODES;
  const float4* p = (const float4*)(h + (size_t)(valid ? n : 0) * NH);
  float hv[NH];
#pragma unroll
  for (int q = 0; q < 4; ++q) {
    float4 v = valid ? p[q] : make_float4(0.f, 0.f, 0.f, 0.f);
    hv[q * 4 + 0] = v.x; hv[q * 4 + 1] = v.y; hv[q * 4 + 2] = v.z; hv[q * 4 + 3] = v.w;
  }
#pragma unroll
  for (int f = 0; f < NH; ++f) {
    float s = hv[f], q = hv[f] * hv[f];
    for (int o = 32; o; o >>= 1) { s += __shfl_xor(s, o, 64); q += __shfl_xor(q, o, 64); }
    if ((tid & 63) == 0) { atomicAdd(&ssum[f], s); atomicAdd(&ssq[f], q); }
  }
  __syncthreads();
  if (tid < NH) {
    atomicAdd(&stats[tid], (double)ssum[tid]);
    atomicAdd(&stats[NH + tid], (double)ssq[tid]);
  }
}

__global__ __launch_bounds__(64) void bn_final_kernel(
    const double* __restrict__ stats, const float* __restrict__ g,
    const float* __restrict__ b, float* __restrict__ sc, float* __restrict__ sh) {
  int f = threadIdx.x;
  if (f < NH) {
    double mu = stats[f] / (double)N_NODES;
    double var = stats[NH + f] / (double)N_NODES - mu * mu;
    float scale = g[f] * (float)(1.0 / sqrt(var + (double)BN_EPS));
    sc[f] = scale;
    sh[f] = b[f] - (float)mu * scale;
  }
}

// ---------------- conv2 init: BN-apply + relu + init/root dots --------------
__global__ __launch_bounds__(256) void conv2_init_kernel(
    const float* __restrict__ h, const float* __restrict__ sc, const float* __restrict__ sh,
    const float* __restrict__ dinv,
    const float* __restrict__ w2i, const float* __restrict__ w2r, const float* __restrict__ b2,
    float* __restrict__ P, float* __restrict__ R) {
  int n = blockIdx.x * blockDim.x + threadIdx.x;
  if (n >= N_NODES) return;
  float u[NH];
#pragma unroll
  for (int f = 0; f < NH; ++f) u[f] = fmaxf(h[(size_t)n * NH + f] * sc[f] + sh[f], 0.f);
  float dn = dinv[n];
#pragma unroll
  for (int k = 0; k < 3; ++k) {
    float r = b2[k], o = 0.f;
#pragma unroll
    for (int f = 0; f < NH; ++f) {
      r += u[f] * w2r[k * NH + f];
      o += u[f] * w2i[k * NH + f];
    }
    R[n * 4 + k] = r;
    P[n * 4 + k] = o * dn;
  }
  R[n * 4 + 3] = 0.f;
  P[n * 4 + 3] = 0.f;
}

// ---------------- conv2 propagate: 16-lane groups, packed CSR ---------------
__global__ __launch_bounds__(256) void conv2_prop_kernel(
    const float* __restrict__ in4, float* __restrict__ out4, float* __restrict__ y,
    const u32* __restrict__ csr, const int* __restrict__ offs,
    const float* __restrict__ dinv,
    const float* __restrict__ R, const float* __restrict__ w2,
    int scale_w2, int final_out) {
  int t = blockIdx.x * 256 + threadIdx.x;
  int n = t >> 4, sub = t & 15;
  float m0 = 1.f, m1 = 1.f, m2 = 1.f;
  if (scale_w2) { m0 = w2[0]; m1 = w2[1]; m2 = w2[2]; }
  int s = offs[n], e = offs[n + 1];
  float a0 = 0.f, a1 = 0.f, a2 = 0.f;
  for (int i = s + sub; i < e; i += 16) {
    u32 ee = csr[i];
    float w = bf2f(ee & 0x7FFFu);
    const float4 v = *(const float4*)(in4 + (size_t)(ee >> 15) * 4);
    a0 += w * v.x;
    a1 += w * v.y;
    a2 += w * v.z;
  }
#pragma unroll
  for (int o = 8; o; o >>= 1) {
    a0 += __shfl_xor(a0, o, 64);
    a1 += __shfl_xor(a1, o, 64);
    a2 += __shfl_xor(a2, o, 64);
  }
  if (sub == 0) {
    float dn = dinv[n];
    a0 = a0 * dn * m0 + R[n * 4 + 0];
    a1 = a1 * dn * m1 + R[n * 4 + 1];
    a2 = a2 * dn * m2 + R[n * 4 + 2];
    if (final_out) {
      float sm = (a0 + a1 + a2) * (1.f / 3.f);
      y[n] = 1.f / (1.f + expf(-sm));
    } else {
      out4[n * 4 + 0] = a0 * dn;
      out4[n * 4 + 1] = a1 * dn;
      out4[n * 4 + 2] = a2 * dn;
      out4[n * 4 + 3] = 0.f;
    }
  }
}

extern "C" void kernel_launch(void* const* d_in, const int* in_sizes, int n_in,
                              void* d_out, int out_size, void* d_ws, size_t ws_size,
                              hipStream_t stream) {
  const float* x   = (const float*)d_in[0];
  const int*   ei  = (const int*)d_in[1];
  const float* ea  = (const float*)d_in[2];
  // d_in[3] = batch (unused)
  const float* w1i = (const float*)d_in[4];
  const float* w1  = (const float*)d_in[5];
  const float* w1r = (const float*)d_in[6];
  const float* b1  = (const float*)d_in[7];
  const float* bng = (const float*)d_in[8];
  const float* bnb = (const float*)d_in[9];
  const float* w2i = (const float*)d_in[10];
  const float* w2  = (const float*)d_in[11];
  const float* w2r = (const float*)d_in[12];
  const float* b2  = (const float*)d_in[13];
  float* y = (float*)d_out;

  const int* row = ei;
  const int* col = ei + N_EDGES;

  char* ws = (char*)d_ws;
  size_t off = 0;
  auto alloc = [&](size_t bytes) -> char* {
    char* p = ws + off;
    off += (bytes + 255) & ~(size_t)255;
    return p;
  };
  u32*    gcur   = (u32*)alloc((size_t)NBUCK * 8 * 4);
  int*    offs   = (int*)alloc((size_t)(N_NODES + 1) * 4);
  float*  dinv   = (float*)alloc((size_t)N_NODES * 4);
  u16*    zx     = (u16*)alloc((size_t)N_NODES * 2);
  double* stats  = (double*)alloc(32 * 8);
  float*  bnsc   = (float*)alloc(16 * 4);
  float*  bnsh   = (float*)alloc(16 * 4);
  int2*   bucketed = (int2*)alloc((size_t)NBUCK * CAP * 8);
  u32*    csr    = (u32*)alloc((size_t)N_EDGES * 4);
  u16*    tA     = (u16*)alloc((size_t)N_NODES * FDIM * 2);
  u16*    tB     = (u16*)alloc((size_t)N_NODES * FDIM * 2);
  float*  hbuf   = (float*)alloc((size_t)N_NODES * NH * 4);
  float*  P2     = (float*)alloc((size_t)N_NODES * 4 * 4);
  float*  Q2     = (float*)alloc((size_t)N_NODES * 4 * 4);
  float*  R2     = (float*)alloc((size_t)N_NODES * 4 * 4);
  (void)ws_size; (void)in_sizes; (void)n_in; (void)out_size;

  hipMemsetAsync(gcur, 0, (size_t)NBUCK * 8 * 4, stream);
  hipMemsetAsync(stats, 0, 32 * 8, stream);

  bucket_scatter_kernel<<<NBLK1, 1024, 0, stream>>>(row, col, ea, gcur, bucketed);
  node_offs_csr_kernel<<<NBUCK, 1024, 0, stream>>>(bucketed, gcur, x, offs, dinv, zx, csr);

  const int NPB = 6250;  // N_NODES*16/256 exactly
  // conv1 layer 1 (rank-1 collapse): merged scalar prop + dense epilogue -> tA
  sprop_mid_kernel<<<NPB, 256, 0, stream>>>(csr, offs, zx, dinv, x, w1i, w1r, b1, w1, tA);
  // conv1 layers 2-4: combined 3-stack propagation; 6250 blocks = 4 nodes/wave
  conv1_prop_kernel<<<6250, 256, 0, stream>>>(tA, tB, nullptr, csr, offs, dinv, x, w1r, b1, w1, 1);
  conv1_prop_kernel<<<6250, 256, 0, stream>>>(tB, tA, nullptr, csr, offs, dinv, x, w1r, b1, w1, 1);
  conv1_prop_kernel<<<6250, 256, 0, stream>>>(tA, nullptr, hbuf, csr, offs, dinv, x, w1r, b1, w1, 0);

  bn_stats_kernel<<<(N_NODES + 255) / 256, 256, 0, stream>>>(hbuf, stats);
  bn_final_kernel<<<1, 64, 0, stream>>>(stats, bng, bnb, bnsc, bnsh);
  conv2_init_kernel<<<(N_NODES + 255) / 256, 256, 0, stream>>>(
      hbuf, bnsc, bnsh, dinv, w2i, w2r, b2, P2, R2);

  conv2_prop_kernel<<<NPB, 256, 0, stream>>>(P2, Q2, nullptr, csr, offs, dinv, R2, w2, 0, 0);
  conv2_prop_kernel<<<NPB, 256, 0, stream>>>(Q2, P2, nullptr, csr, offs, dinv, R2, w2, 1, 0);
  conv2_prop_kernel<<<NPB, 256, 0, stream>>>(P2, Q2, nullptr, csr, offs, dinv, R2, w2, 1, 0);
  conv2_prop_kernel<<<NPB, 256, 0, stream>>>(Q2, P2, y, csr, offs, dinv, R2, w2, 1, 1);
}